// Round 1
// 777.666 us; speedup vs baseline: 1.1456x; 1.1456x over previous
//
#include <hip/hip_runtime.h>
#include <math.h>

// Problem constants
constexpr int Bb   = 16;
constexpr int Cc   = 256;
constexpr int Hh   = 128;
constexpr int Ww   = 128;
constexpr int NPIX = Hh * Ww;     // 16384
constexpr int RED  = 64;
constexpr int MID  = 32;
constexpr float SCALE = 0.35355339059327373f;  // 8^-0.5

// ---------------------------------------------------------------------------
// Prep: fold BN_in into in_proj (transposed [c][r]); fold o_w + sigmoid(alpha)
// * BN_out into out_proj as WtCmb[m][co] (32x256) and bcomb[co].
// ---------------------------------------------------------------------------
__global__ __launch_bounds__(256) void prep_kernel(
    const float* __restrict__ bn_in_gamma, const float* __restrict__ bn_in_beta,
    const float* __restrict__ bn_in_mean,  const float* __restrict__ bn_in_var,
    const float* __restrict__ in_proj_w,
    const float* __restrict__ out_proj_w,
    const float* __restrict__ bn_out_gamma, const float* __restrict__ bn_out_beta,
    const float* __restrict__ bn_out_mean,  const float* __restrict__ bn_out_var,
    const float* __restrict__ o_w, const float* __restrict__ o_b,
    const float* __restrict__ alpha,
    float* __restrict__ WtIn,  float* __restrict__ beff_in,
    float* __restrict__ WtCmb, float* __restrict__ bcomb) {
  int idx = blockIdx.x * 256 + threadIdx.x;
  float s = 1.0f / (1.0f + __expf(-alpha[0]));
  if (idx < Cc * RED) {  // WtIn[c][r] = in_proj_w[r][c] * inv(c)
    int c = idx >> 6, r = idx & 63;
    float inv = bn_in_gamma[c] * rsqrtf(bn_in_var[c] + 1e-5f);
    WtIn[idx] = in_proj_w[r * Cc + c] * inv;
  }
  if (idx < MID * Cc) {  // WtCmb[m][co] = sum_t s*inv2(co)*Wout[co][g*16+t]*ow[g][t][j]
    int m = idx >> 8, co = idx & 255;
    int g = m >> 3, j = m & 7;
    float inv2 = bn_out_gamma[co] * rsqrtf(bn_out_var[co] + 1e-5f);
    float a = 0.f;
    #pragma unroll
    for (int t = 0; t < 16; t++)
      a += out_proj_w[co * RED + g * 16 + t] * o_w[g * 128 + t * 8 + j];
    WtCmb[idx] = s * inv2 * a;
  }
  if (idx < RED) {       // beff_in[r] = sum_c in_proj_w[r][c]*(beta - mean*inv)
    float acc = 0.f;
    for (int c = 0; c < Cc; c++) {
      float inv = bn_in_gamma[c] * rsqrtf(bn_in_var[c] + 1e-5f);
      acc += in_proj_w[idx * Cc + c] * (bn_in_beta[c] - bn_in_mean[c] * inv);
    }
    beff_in[idx] = acc;
  }
  if (idx < Cc) {        // bcomb[co] = s*((beta-mean*inv2) + inv2*sum_r Wout[co][r]*o_b[r])
    float inv2 = bn_out_gamma[idx] * rsqrtf(bn_out_var[idx] + 1e-5f);
    float a = bn_out_beta[idx] - bn_out_mean[idx] * inv2;
    for (int r = 0; r < RED; r++)
      a += inv2 * out_proj_w[idx * RED + r] * o_b[r];
    bcomb[idx] = s * a;
  }
}

// ---------------------------------------------------------------------------
// Fused: per 8x8 window — in_proj GEMM -> attention -> (o_w∘out_proj) + residual.
// 256 threads (4 waves). Wave wv owns 16 output rows in GEMM phases; lane = token n.
// Weights read via wave-uniform scalar loads (K$), X/Y via 1 ds_read_b32 per 16 FMA.
// LDS 13440 floats (52.5 KB) -> 3 blocks/CU.
// ---------------------------------------------------------------------------
__global__ __launch_bounds__(256, 3) void fused_kernel(
    const float* __restrict__ x,
    const float* __restrict__ WtIn,    // [256][64]
    const float* __restrict__ beff_in, // [64]
    const float* __restrict__ qk_base_w, const float* __restrict__ q_head_w,
    const float* __restrict__ q_head_b,  const float* __restrict__ k_head_w,
    const float* __restrict__ k_head_b,  const float* __restrict__ v_w,
    const float* __restrict__ v_b,
    const float* __restrict__ WtCmb,   // [32][256]
    const float* __restrict__ bcomb,   // [256]
    float* __restrict__ out) {
  __shared__ float smem[13440];
  float* XR    = smem;          // [64][64] x_red window (r-major)
  float* base_ = smem + 4096;   // [32][64]; later aliased by outT
  float* kT    = smem + 6144;   // [64][33] padded
  float* vT    = smem + 8256;   // [64][33] padded
  float* qkw   = smem + 10368;  // 512
  float* vw    = smem + 10880;  // 512
  float* qhw   = smem + 11392;  // 1024
  float* khw   = smem + 12416;  // 1024
  float* Xc    = smem + 4096;   // [64][64] P1 channel-chunk staging (aliases base/kT)
  float* outT  = base_;         // [32][64]

  const int bid = blockIdx.x;
  const int w   = ((bid & 7) << 9) | (bid >> 3);  // XCD swizzle (bijective, 4096=8*512)
  const int b   = w >> 8;
  const int wh  = (w >> 4) & 15, wwi = w & 15;
  const int tid  = threadIdx.x;
  const int lane = tid & 63;
  const int wv   = __builtin_amdgcn_readfirstlane(tid >> 6);

  const float* xwin = x + ((size_t)b * Cc) * NPIX + (wh * 8) * Ww + wwi * 8;

  // ---- P1: XR[r][n] = beff_in[r] + sum_c WtIn[c][r] * x[c][n], K chunked by 64 ----
  float acc[16];
  #pragma unroll
  for (int t = 0; t < 16; t++) acc[t] = beff_in[wv * 16 + t];
  for (int ch = 0; ch < 4; ch++) {
    __syncthreads();
    for (int e = tid; e < 1024; e += 256) {   // stage Xc[cc][n] as float4 rows
      int cc = e >> 4, nq = e & 15;
      int i = nq >> 1, half = nq & 1;
      float4 xv4 = *(const float4*)(xwin + (size_t)(ch * 64 + cc) * NPIX + i * Ww + half * 4);
      *(float4*)(Xc + cc * 64 + nq * 4) = xv4;
    }
    __syncthreads();
    const float* Wp = WtIn + (size_t)(ch * 64) * 64 + wv * 16;
    #pragma unroll
    for (int k = 0; k < 64; k++) {
      float xv = Xc[k * 64 + lane];
      const float* wk = Wp + k * 64;   // wave-uniform -> s_load_dwordx16
      #pragma unroll
      for (int t = 0; t < 16; t++) acc[t] = fmaf(wk[t], xv, acc[t]);
    }
  }
  // write XR (region untouched by staging); stage small attn weights (region disjoint from Xc)
  #pragma unroll
  for (int t = 0; t < 16; t++) XR[(wv * 16 + t) * 64 + lane] = acc[t];
  for (int e = tid; e < 512; e += 256)  { qkw[e] = qk_base_w[e]; vw[e] = v_w[e]; }
  for (int e = tid; e < 1024; e += 256) { qhw[e] = q_head_w[e]; khw[e] = k_head_w[e]; }
  __syncthreads();

  // ---- S2: base[m][n] = sum_{i<16} qkw[g,m%8,i] * XR[g*16+i][n] ----
  for (int e = tid; e < 2048; e += 256) {
    int m = e >> 6, n = e & 63, g = m >> 3;
    const float* wp = qkw + (g * 8 + (m & 7)) * 16;
    const float* xp = XR + g * 16 * 64 + n;
    float a = 0.f;
    #pragma unroll
    for (int i = 0; i < 16; i++) a += wp[i] * xp[i * 64];
    base_[e] = a;
  }
  __syncthreads();

  // ---- S3: kT[n][m] (K=32 head matmul), vT[n][m] (grouped conv K=16) ----
  for (int e = tid; e < 2048; e += 256) {
    int m = e >> 6, n = e & 63, g = m >> 3;
    float a = k_head_b[m];
    const float* wp = khw + m * 32;
    #pragma unroll
    for (int i = 0; i < 32; i++) a += wp[i] * base_[i * 64 + n];
    kT[n * 33 + m] = a;
    float av = v_b[m];
    const float* vp = vw + (g * 8 + (m & 7)) * 16;
    const float* xp = XR + g * 16 * 64 + n;
    #pragma unroll
    for (int i = 0; i < 16; i++) av += vp[i] * xp[i * 64];
    vT[n * 33 + m] = av;
  }
  __syncthreads();

  // ---- S4: one thread per (head wv, query token lane) ----
  float qv[8];
  {
    float a[8];
    #pragma unroll
    for (int d = 0; d < 8; d++) a[d] = q_head_b[wv * 8 + d];
    #pragma unroll
    for (int i = 0; i < 32; i++) {
      float bv = base_[i * 64 + lane];
      #pragma unroll
      for (int d = 0; d < 8; d++) a[d] += qhw[(wv * 8 + d) * 32 + i] * bv;
    }
    #pragma unroll
    for (int d = 0; d < 8; d++) qv[d] = a[d] * SCALE;
  }
  float s[64];
  float mx = -1e30f;
  const float* kTh = kT + wv * 8;
  #pragma unroll
  for (int j = 0; j < 64; j++) {
    const float* kr = kTh + j * 33;
    float a = 0.f;
    #pragma unroll
    for (int d = 0; d < 8; d++) a += qv[d] * kr[d];
    s[j] = a;
    mx = fmaxf(mx, a);
  }
  float sum = 0.f;
  #pragma unroll
  for (int j = 0; j < 64; j++) { float e = __expf(s[j] - mx); s[j] = e; sum += e; }
  float inv = 1.0f / sum;
  float o[8] = {0, 0, 0, 0, 0, 0, 0, 0};
  const float* vTh = vT + wv * 8;
  #pragma unroll
  for (int j = 0; j < 64; j++) {
    float p = s[j];
    const float* vr = vTh + j * 33;
    #pragma unroll
    for (int d = 0; d < 8; d++) o[d] += p * vr[d];
  }
  __syncthreads();  // all base_/kT reads done before outT (=base_) write
  #pragma unroll
  for (int d = 0; d < 8; d++) outT[(wv * 8 + d) * 64 + lane] = o[d] * inv;
  __syncthreads();

  // ---- P3: out[co][n] = x[co][n] + bcomb[co] + sum_{m<32} WtCmb[m][co]*outT[m][n] ----
  const int ii = lane >> 3, jj = lane & 7;
  const size_t pixoff = (size_t)(wh * 8 + ii) * Ww + wwi * 8 + jj;
  for (int cc = 0; cc < 4; cc++) {
    const int co0 = cc * 64 + wv * 16;
    float oacc[16];
    #pragma unroll
    for (int t = 0; t < 16; t++) oacc[t] = bcomb[co0 + t];
    const float* Wp = WtCmb + co0;
    #pragma unroll
    for (int k = 0; k < 32; k++) {
      float yv = outT[k * 64 + lane];
      const float* wk = Wp + k * 256;  // wave-uniform -> s_load_dwordx16
      #pragma unroll
      for (int t = 0; t < 16; t++) oacc[t] = fmaf(wk[t], yv, oacc[t]);
    }
    const float* xr = x   + ((size_t)b * Cc + co0) * NPIX + pixoff;
    float*       orr = out + ((size_t)b * Cc + co0) * NPIX + pixoff;
    #pragma unroll
    for (int t = 0; t < 16; t++) {
      orr[(size_t)t * NPIX] = oacc[t] + xr[(size_t)t * NPIX];
    }
  }
}

// ---------------------------------------------------------------------------
extern "C" void kernel_launch(void* const* d_in, const int* in_sizes, int n_in,
                              void* d_out, int out_size, void* d_ws, size_t ws_size,
                              hipStream_t stream) {
  const float* x           = (const float*)d_in[0];
  const float* bn_in_gamma = (const float*)d_in[1];
  const float* bn_in_beta  = (const float*)d_in[2];
  const float* bn_in_mean  = (const float*)d_in[3];
  const float* bn_in_var   = (const float*)d_in[4];
  const float* in_proj_w   = (const float*)d_in[5];
  const float* qk_base_w   = (const float*)d_in[6];
  const float* q_head_w    = (const float*)d_in[7];
  const float* q_head_b    = (const float*)d_in[8];
  const float* k_head_w    = (const float*)d_in[9];
  const float* k_head_b    = (const float*)d_in[10];
  const float* v_w         = (const float*)d_in[11];
  const float* v_b         = (const float*)d_in[12];
  const float* o_w         = (const float*)d_in[13];
  const float* o_b         = (const float*)d_in[14];
  const float* out_proj_w  = (const float*)d_in[15];
  const float* bn_out_gamma= (const float*)d_in[16];
  const float* bn_out_beta = (const float*)d_in[17];
  const float* bn_out_mean = (const float*)d_in[18];
  const float* bn_out_var  = (const float*)d_in[19];
  const float* alpha       = (const float*)d_in[20];

  float* ws = (float*)d_ws;
  float* WtIn    = ws;              // 256*64 = 16384
  float* beff_in = ws + 16384;      // 64
  float* WtCmb   = ws + 16448;      // 32*256 = 8192
  float* bcomb   = ws + 24640;      // 256
  (void)ws_size; (void)in_sizes; (void)n_in; (void)out_size;

  prep_kernel<<<64, 256, 0, stream>>>(
      bn_in_gamma, bn_in_beta, bn_in_mean, bn_in_var, in_proj_w,
      out_proj_w, bn_out_gamma, bn_out_beta, bn_out_mean, bn_out_var,
      o_w, o_b, alpha, WtIn, beff_in, WtCmb, bcomb);

  fused_kernel<<<4096, 256, 0, stream>>>(
      x, WtIn, beff_in, qk_base_w, q_head_w, q_head_b, k_head_w, k_head_b,
      v_w, v_b, WtCmb, bcomb, (float*)d_out);
}

// Round 2
// 765.883 us; speedup vs baseline: 1.1633x; 1.0154x over previous
//
#include <hip/hip_runtime.h>
#include <math.h>

// Problem constants
constexpr int Bb   = 16;
constexpr int Cc   = 256;
constexpr int Hh   = 128;
constexpr int Ww   = 128;
constexpr int NPIX = Hh * Ww;     // 16384
constexpr int RED  = 64;
constexpr int MID  = 32;
constexpr float SCALE = 0.35355339059327373f;  // 8^-0.5

// ---------------------------------------------------------------------------
// Prep: fold BN_in into in_proj (transposed [c][r]); fold o_w + sigmoid(alpha)
// * BN_out into out_proj as WtCmb[m][co] (32x256) and bcomb[co].
// ---------------------------------------------------------------------------
__global__ __launch_bounds__(256) void prep_kernel(
    const float* __restrict__ bn_in_gamma, const float* __restrict__ bn_in_beta,
    const float* __restrict__ bn_in_mean,  const float* __restrict__ bn_in_var,
    const float* __restrict__ in_proj_w,
    const float* __restrict__ out_proj_w,
    const float* __restrict__ bn_out_gamma, const float* __restrict__ bn_out_beta,
    const float* __restrict__ bn_out_mean,  const float* __restrict__ bn_out_var,
    const float* __restrict__ o_w, const float* __restrict__ o_b,
    const float* __restrict__ alpha,
    float* __restrict__ WtIn,  float* __restrict__ beff_in,
    float* __restrict__ WtCmb, float* __restrict__ bcomb) {
  int idx = blockIdx.x * 256 + threadIdx.x;
  float s = 1.0f / (1.0f + __expf(-alpha[0]));
  if (idx < Cc * RED) {  // WtIn[c][r] = in_proj_w[r][c] * inv(c)
    int c = idx >> 6, r = idx & 63;
    float inv = bn_in_gamma[c] * rsqrtf(bn_in_var[c] + 1e-5f);
    WtIn[idx] = in_proj_w[r * Cc + c] * inv;
  }
  if (idx < MID * Cc) {  // WtCmb[m][co] = sum_t s*inv2(co)*Wout[co][g*16+t]*ow[g][t][j]
    int m = idx >> 8, co = idx & 255;
    int g = m >> 3, j = m & 7;
    float inv2 = bn_out_gamma[co] * rsqrtf(bn_out_var[co] + 1e-5f);
    float a = 0.f;
    #pragma unroll
    for (int t = 0; t < 16; t++)
      a += out_proj_w[co * RED + g * 16 + t] * o_w[g * 128 + t * 8 + j];
    WtCmb[idx] = s * inv2 * a;
  }
  if (idx < RED) {       // beff_in[r] = sum_c in_proj_w[r][c]*(beta - mean*inv)
    float acc = 0.f;
    for (int c = 0; c < Cc; c++) {
      float inv = bn_in_gamma[c] * rsqrtf(bn_in_var[c] + 1e-5f);
      acc += in_proj_w[idx * Cc + c] * (bn_in_beta[c] - bn_in_mean[c] * inv);
    }
    beff_in[idx] = acc;
  }
  if (idx < Cc) {        // bcomb[co] = s*((beta-mean*inv2) + inv2*sum_r Wout[co][r]*o_b[r])
    float inv2 = bn_out_gamma[idx] * rsqrtf(bn_out_var[idx] + 1e-5f);
    float a = bn_out_beta[idx] - bn_out_mean[idx] * inv2;
    for (int r = 0; r < RED; r++)
      a += inv2 * out_proj_w[idx * RED + r] * o_b[r];
    bcomb[idx] = s * a;
  }
}

// ---------------------------------------------------------------------------
// Fused per-window kernel, v2.
//  - All weights via wave-uniform scalar loads (no LDS weight staging).
//  - base/q computed in registers per wave (head); kT/vT wave-private LDS tiles,
//    stride 36, read as uniform-broadcast ds_read_b128 in the attention loop.
//  - LDS 34 KB (Xc aliased under kT/vT, outT under XR) -> 4 blocks/CU.
//  - P1 x-staging register-double-buffered (loads for chunk ch+1 in flight
//    during chunk ch compute).
// ---------------------------------------------------------------------------
__global__ __launch_bounds__(256, 4) void fused_kernel(
    const float* __restrict__ x,
    const float* __restrict__ WtIn,    // [256][64]
    const float* __restrict__ beff_in, // [64]
    const float* __restrict__ qk_base_w, const float* __restrict__ q_head_w,
    const float* __restrict__ q_head_b,  const float* __restrict__ k_head_w,
    const float* __restrict__ k_head_b,  const float* __restrict__ v_w,
    const float* __restrict__ v_b,
    const float* __restrict__ WtCmb,   // [32][256]
    const float* __restrict__ bcomb,   // [256]
    float* __restrict__ out) {
  __shared__ float smem[8704];        // 34816 B
  float* kT   = smem;                 // [64][36] (stride 36 keeps float4 align)
  float* vT   = smem + 2304;          // [64][36]
  float* Xc   = smem;                 // [64][64] P1 staging (dead before kT/vT writes)
  float* XR   = smem + 4608;          // [64][64]
  float* outT = smem + 4608;          // [32][64] (XR dead when written)

  const int bid = blockIdx.x;
  const int w   = ((bid & 7) << 9) | (bid >> 3);  // XCD swizzle (bijective, 4096=8*512)
  const int b   = w >> 8;
  const int wh  = (w >> 4) & 15, wwi = w & 15;
  const int tid  = threadIdx.x;
  const int lane = tid & 63;
  const int wv   = __builtin_amdgcn_readfirstlane(tid >> 6);

  const float* xwin = x + ((size_t)b * Cc) * NPIX + (wh * 8) * Ww + wwi * 8;

  // ---- P1: XR[r][n] = beff_in[r] + sum_c WtIn[c][r] * x[c][n], K chunked by 64 ----
  float acc[16];
  #pragma unroll
  for (int t = 0; t < 16; t++) acc[t] = beff_in[wv * 16 + t];

  const int s_cc = tid >> 4, s_nq = tid & 15;          // thread's staging slot (i adds 16 to cc)
  const size_t s_goff = (size_t)s_cc * NPIX + (s_nq >> 1) * Ww + (s_nq & 1) * 4;

  float4 pre[4];
  #pragma unroll
  for (int i = 0; i < 4; i++)
    pre[i] = *(const float4*)(xwin + (size_t)(0 * 64 + i * 16) * NPIX + s_goff);

  #pragma unroll
  for (int ch = 0; ch < 4; ch++) {
    __syncthreads();                                   // Xc free (prev compute done)
    #pragma unroll
    for (int i = 0; i < 4; i++)
      *(float4*)(Xc + (s_cc + i * 16) * 64 + s_nq * 4) = pre[i];
    if (ch < 3) {                                      // next chunk in flight during compute
      #pragma unroll
      for (int i = 0; i < 4; i++)
        pre[i] = *(const float4*)(xwin + (size_t)((ch + 1) * 64 + i * 16) * NPIX + s_goff);
    }
    __syncthreads();                                   // Xc ready
    const float* Wp = WtIn + (size_t)(ch * 64) * 64 + wv * 16;
    #pragma unroll
    for (int k = 0; k < 64; k++) {
      float xv = Xc[k * 64 + lane];
      const float* wk = Wp + k * 64;                   // wave-uniform -> s_load
      #pragma unroll
      for (int t = 0; t < 16; t++) acc[t] = fmaf(wk[t], xv, acc[t]);
    }
  }
  #pragma unroll
  for (int t = 0; t < 16; t++) XR[(wv * 16 + t) * 64 + lane] = acc[t];
  __syncthreads();

  // ---- Merged S2+S3+Q: base[0..31] in registers (per wave), then qv, kT row, vT row ----
  float base_[32];
  #pragma unroll
  for (int g = 0; g < 4; g++) {
    float xr[16];
    #pragma unroll
    for (int t = 0; t < 16; t++) xr[t] = XR[(g * 16 + t) * 64 + lane];
    #pragma unroll
    for (int o = 0; o < 8; o++) {
      const float* wp = qk_base_w + (g * 8 + o) * 16;  // uniform -> s_load
      float a = 0.f;
      #pragma unroll
      for (int t = 0; t < 16; t++) a += wp[t] * xr[t];
      base_[g * 8 + o] = a;
    }
  }
  float vacc[8];
  {
    float xr[16];
    #pragma unroll
    for (int t = 0; t < 16; t++) xr[t] = XR[(wv * 16 + t) * 64 + lane];
    #pragma unroll
    for (int d = 0; d < 8; d++) {
      const float* vp = v_w + (wv * 8 + d) * 16;       // uniform
      float a = v_b[wv * 8 + d];
      #pragma unroll
      for (int t = 0; t < 16; t++) a += vp[t] * xr[t];
      vacc[d] = a;
    }
  }
  float qv[8];
  #pragma unroll
  for (int d = 0; d < 8; d++) {
    const float* wp = q_head_w + (wv * 8 + d) * 32;    // uniform
    float a = q_head_b[wv * 8 + d];
    #pragma unroll
    for (int i = 0; i < 32; i++) a += wp[i] * base_[i];
    qv[d] = a * SCALE;
  }
  float kacc[8];
  #pragma unroll
  for (int d = 0; d < 8; d++) {
    const float* wp = k_head_w + (wv * 8 + d) * 32;    // uniform
    float a = k_head_b[wv * 8 + d];
    #pragma unroll
    for (int i = 0; i < 32; i++) a += wp[i] * base_[i];
    kacc[d] = a;
  }
  // kT/vT: wave-private columns [8wv, 8wv+8) for every token (lane)
  *(float4*)(kT + lane * 36 + wv * 8)     = make_float4(kacc[0], kacc[1], kacc[2], kacc[3]);
  *(float4*)(kT + lane * 36 + wv * 8 + 4) = make_float4(kacc[4], kacc[5], kacc[6], kacc[7]);
  *(float4*)(vT + lane * 36 + wv * 8)     = make_float4(vacc[0], vacc[1], vacc[2], vacc[3]);
  *(float4*)(vT + lane * 36 + wv * 8 + 4) = make_float4(vacc[4], vacc[5], vacc[6], vacc[7]);
  __syncthreads();   // also fences all XR reads before outT (=XR region) writes below

  // ---- S4: head = wv, query token = lane; K/V rows via uniform-broadcast b128 ----
  float s_[64];
  float mx = -1e30f;
  const float* kTh = kT + wv * 8;
  #pragma unroll
  for (int j = 0; j < 64; j++) {
    float4 k0 = *(const float4*)(kTh + j * 36);
    float4 k1 = *(const float4*)(kTh + j * 36 + 4);
    float a = 0.f;
    a += qv[0] * k0.x; a += qv[1] * k0.y; a += qv[2] * k0.z; a += qv[3] * k0.w;
    a += qv[4] * k1.x; a += qv[5] * k1.y; a += qv[6] * k1.z; a += qv[7] * k1.w;
    s_[j] = a;
    mx = fmaxf(mx, a);
  }
  float sum = 0.f;
  #pragma unroll
  for (int j = 0; j < 64; j++) { float e = __expf(s_[j] - mx); s_[j] = e; sum += e; }
  float inv = 1.0f / sum;
  float o[8] = {0, 0, 0, 0, 0, 0, 0, 0};
  const float* vTh = vT + wv * 8;
  #pragma unroll
  for (int j = 0; j < 64; j++) {
    float p = s_[j];
    float4 v0 = *(const float4*)(vTh + j * 36);
    float4 v1 = *(const float4*)(vTh + j * 36 + 4);
    o[0] += p * v0.x; o[1] += p * v0.y; o[2] += p * v0.z; o[3] += p * v0.w;
    o[4] += p * v1.x; o[5] += p * v1.y; o[6] += p * v1.z; o[7] += p * v1.w;
  }
  #pragma unroll
  for (int d = 0; d < 8; d++) outT[(wv * 8 + d) * 64 + lane] = o[d] * inv;
  __syncthreads();

  // ---- P3: out[co][n] = x[co][n] + bcomb[co] + sum_{m<32} WtCmb[m][co]*outT[m][n] ----
  float yv[32];
  #pragma unroll
  for (int k = 0; k < 32; k++) yv[k] = outT[k * 64 + lane];
  const int ii = lane >> 3, jj = lane & 7;
  const size_t pixoff = (size_t)(wh * 8 + ii) * Ww + wwi * 8 + jj;
  for (int cc = 0; cc < 4; cc++) {
    const int co0 = cc * 64 + wv * 16;
    float oacc[16];
    #pragma unroll
    for (int t = 0; t < 16; t++) oacc[t] = bcomb[co0 + t];
    const float* Wp = WtCmb + co0;
    #pragma unroll
    for (int k = 0; k < 32; k++) {
      float y = yv[k];
      const float* wk = Wp + k * 256;                  // wave-uniform -> s_load
      #pragma unroll
      for (int t = 0; t < 16; t++) oacc[t] = fmaf(wk[t], y, oacc[t]);
    }
    const float* xr  = x   + ((size_t)b * Cc + co0) * NPIX + pixoff;
    float*       orr = out + ((size_t)b * Cc + co0) * NPIX + pixoff;
    #pragma unroll
    for (int t = 0; t < 16; t++)
      orr[(size_t)t * NPIX] = oacc[t] + xr[(size_t)t * NPIX];
  }
}

// ---------------------------------------------------------------------------
extern "C" void kernel_launch(void* const* d_in, const int* in_sizes, int n_in,
                              void* d_out, int out_size, void* d_ws, size_t ws_size,
                              hipStream_t stream) {
  const float* x           = (const float*)d_in[0];
  const float* bn_in_gamma = (const float*)d_in[1];
  const float* bn_in_beta  = (const float*)d_in[2];
  const float* bn_in_mean  = (const float*)d_in[3];
  const float* bn_in_var   = (const float*)d_in[4];
  const float* in_proj_w   = (const float*)d_in[5];
  const float* qk_base_w   = (const float*)d_in[6];
  const float* q_head_w    = (const float*)d_in[7];
  const float* q_head_b    = (const float*)d_in[8];
  const float* k_head_w    = (const float*)d_in[9];
  const float* k_head_b    = (const float*)d_in[10];
  const float* v_w         = (const float*)d_in[11];
  const float* v_b         = (const float*)d_in[12];
  const float* o_w         = (const float*)d_in[13];
  const float* o_b         = (const float*)d_in[14];
  const float* out_proj_w  = (const float*)d_in[15];
  const float* bn_out_gamma= (const float*)d_in[16];
  const float* bn_out_beta = (const float*)d_in[17];
  const float* bn_out_mean = (const float*)d_in[18];
  const float* bn_out_var  = (const float*)d_in[19];
  const float* alpha       = (const float*)d_in[20];

  float* ws = (float*)d_ws;
  float* WtIn    = ws;              // 256*64 = 16384
  float* beff_in = ws + 16384;      // 64
  float* WtCmb   = ws + 16448;      // 32*256 = 8192
  float* bcomb   = ws + 24640;      // 256
  (void)ws_size; (void)in_sizes; (void)n_in; (void)out_size;

  prep_kernel<<<64, 256, 0, stream>>>(
      bn_in_gamma, bn_in_beta, bn_in_mean, bn_in_var, in_proj_w,
      out_proj_w, bn_out_gamma, bn_out_beta, bn_out_mean, bn_out_var,
      o_w, o_b, alpha, WtIn, beff_in, WtCmb, bcomb);

  fused_kernel<<<4096, 256, 0, stream>>>(
      x, WtIn, beff_in, qk_base_w, q_head_w, q_head_b, k_head_w, k_head_b,
      v_w, v_b, WtCmb, bcomb, (float*)d_out);
}